// Round 1
// baseline (652.422 us; speedup 1.0000x reference)
//
#include <hip/hip_runtime.h>
#include <hip/hip_bf16.h>
#include <stdint.h>

#define NB 4096
#define NCOL 100
#define NCOND 64
#define NTOTAL 6400
#define NRODT 1600
#define NEST 160
#define NFOR 100
#define NHID 128
#define NCLS 10
#define GEPS 1e-5f

// ---------------------------------------------------------------------------
// K1: fused ConditionGeneration + perm + phi_2  -> rODT logits w[b, g]
// One block handles 8 samples so per-group weights load once per 8 b.
// ---------------------------------------------------------------------------
__global__ __launch_bounds__(256) void k1_w(
    const float* __restrict__ x, const float* __restrict__ w1,
    const float* __restrict__ b1, const int* __restrict__ perm,
    const float* __restrict__ gn1w, const float* __restrict__ gn1b,
    const float* __restrict__ c2w, const float* __restrict__ c2b,
    const float* __restrict__ gn2w, const float* __restrict__ gn2b,
    const float* __restrict__ c3w, const float* __restrict__ c3b,
    float* __restrict__ wout)
{
  __shared__ float xl[8][NCOL];
  const int b0 = blockIdx.x * 8;
  for (int i = threadIdx.x; i < 8 * NCOL; i += 256)
    xl[i / NCOL][i % NCOL] = x[(size_t)b0 * NCOL + i];
  __syncthreads();

  for (int g = threadIdx.x; g < NRODT; g += 256) {
    const int4 p4 = *(const int4*)(perm + 4 * g);
    const int pv[4] = {p4.x, p4.y, p4.z, p4.w};
    float w1v[4], b1v[4];
    int pc[4];
#pragma unroll
    for (int i = 0; i < 4; i++) {
      unsigned p = (unsigned)pv[i];
      unsigned j = p / 100u;          // flat idx = j*100 + c after transpose
      unsigned c = p - j * 100u;
      pc[i] = (int)c;
      w1v[i] = w1[c * NCOND + j];
      b1v[i] = b1[c * NCOND + j];
    }
    const float4 g1w = *(const float4*)(gn1w + 4 * g);
    const float4 g1b = *(const float4*)(gn1b + 4 * g);
    const float4 cw0 = *(const float4*)(c2w + 16 * g);
    const float4 cw1 = *(const float4*)(c2w + 16 * g + 4);
    const float4 cw2 = *(const float4*)(c2w + 16 * g + 8);
    const float4 cw3 = *(const float4*)(c2w + 16 * g + 12);
    const float4 cbv = *(const float4*)(c2b + 4 * g);
    const float4 g2w = *(const float4*)(gn2w + 4 * g);
    const float4 g2b = *(const float4*)(gn2b + 4 * g);
    const float4 c3v = *(const float4*)(c3w + 4 * g);
    const float c3bv = c3b[g];

    for (int bb = 0; bb < 8; bb++) {
      float O[4];
#pragma unroll
      for (int i = 0; i < 4; i++) {
        float a = xl[bb][pc[i]] * w1v[i] + b1v[i];
        O[i] = 1.0f / (1.0f + __expf(-a));   // sigmoid
      }
      // group norm over the 4 channels of this group
      float mu = 0.25f * (O[0] + O[1] + O[2] + O[3]);
      float d[4], var = 0.f;
#pragma unroll
      for (int i = 0; i < 4; i++) { d[i] = O[i] - mu; var += d[i] * d[i]; }
      float rs = rsqrtf(0.25f * var + GEPS);
      float xn0 = d[0] * rs * g1w.x + g1b.x;
      float xn1 = d[1] * rs * g1w.y + g1b.y;
      float xn2 = d[2] * rs * g1w.z + g1b.z;
      float xn3 = d[3] * rs * g1w.w + g1b.w;
      // grouped 4->4 conv + bias + relu
      float h[4];
      h[0] = xn0*cw0.x + xn1*cw1.x + xn2*cw2.x + xn3*cw3.x + cbv.x;
      h[1] = xn0*cw0.y + xn1*cw1.y + xn2*cw2.y + xn3*cw3.y + cbv.y;
      h[2] = xn0*cw0.z + xn1*cw1.z + xn2*cw2.z + xn3*cw3.z + cbv.z;
      h[3] = xn0*cw0.w + xn1*cw1.w + xn2*cw2.w + xn3*cw3.w + cbv.w;
#pragma unroll
      for (int i = 0; i < 4; i++) h[i] = fmaxf(h[i], 0.f);
      // second group norm
      float mu2 = 0.25f * (h[0] + h[1] + h[2] + h[3]);
      float e[4], var2 = 0.f;
#pragma unroll
      for (int i = 0; i < 4; i++) { e[i] = h[i] - mu2; var2 += e[i] * e[i]; }
      float rs2 = rsqrtf(0.25f * var2 + GEPS);
      float hn0 = e[0] * rs2 * g2w.x + g2b.x;
      float hn1 = e[1] * rs2 * g2w.y + g2b.y;
      float hn2 = e[2] * rs2 * g2w.z + g2b.z;
      float hn3 = e[3] * rs2 * g2w.w + g2b.w;
      // grouped 4->1 conv
      float wv = hn0*c3v.x + hn1*c3v.y + hn2*c3v.z + hn3*c3v.w + c3bv;
      wout[(size_t)(b0 + bb) * NRODT + g] = wv;
    }
  }
}

// ---------------------------------------------------------------------------
// K2: per (b, f) gather + softmax over 160 estimators -> ws bf16 [B,100,160]
// w row staged in LDS so the random gathers are LDS, not global.
// ---------------------------------------------------------------------------
__global__ __launch_bounds__(256) void k2_softmax(
    const float* __restrict__ wv, const int* __restrict__ swr,
    __hip_bfloat16* __restrict__ wsout)
{
  __shared__ float wl[NRODT];
  const int b = blockIdx.x;
  for (int i = threadIdx.x; i < NRODT; i += 256) wl[i] = wv[(size_t)b * NRODT + i];
  __syncthreads();

  const int wave = threadIdx.x >> 6, lane = threadIdx.x & 63;
  for (int f = wave; f < NFOR; f += 4) {
    const int* sw = swr + f * NEST;
    float v0 = wl[sw[lane]];
    float v1 = wl[sw[lane + 64]];
    float v2 = (lane < 32) ? wl[sw[lane + 128]] : -1e30f;
    float m = fmaxf(fmaxf(v0, v1), v2);
#pragma unroll
    for (int off = 32; off; off >>= 1) m = fmaxf(m, __shfl_xor(m, off));
    float e0 = __expf(v0 - m), e1 = __expf(v1 - m);
    float e2 = (lane < 32) ? __expf(v2 - m) : 0.0f;
    float s = e0 + e1 + e2;
#pragma unroll
    for (int off = 32; off; off >>= 1) s += __shfl_xor(s, off);
    float inv = 1.0f / s;
    __hip_bfloat16* o = wsout + ((size_t)b * NFOR + f) * NEST;
    o[lane]      = __float2bfloat16(e0 * inv);
    o[lane + 64] = __float2bfloat16(e1 * inv);
    if (lane < 32) o[lane + 128] = __float2bfloat16(e2 * inv);
  }
}

// ---------------------------------------------------------------------------
// K3: fused  F = ws @ Ep  -> LN1 -> fc1+ReLU -> LN2 -> fc2 -> mean over f.
// Block = (forest f, tile of 64 b).  256 threads, thread tile 4 rows x 8 cols.
// LDS: lsA = ws tile (64x161 f32) reused as Fn tile (stride 132);
//      lsE = streamed B chunks 8x128 (skewed) reused for fc2_w.
// ~46 KB LDS -> 3 blocks/CU.
// ---------------------------------------------------------------------------
__global__ __launch_bounds__(256) void k3_fused(
    const __hip_bfloat16* __restrict__ wsb, const int* __restrict__ swr,
    const float* __restrict__ E,
    const float* __restrict__ ln1w, const float* __restrict__ ln1b,
    const float* __restrict__ fc1w, const float* __restrict__ fc1b,
    const float* __restrict__ ln2w, const float* __restrict__ ln2b,
    const float* __restrict__ fc2w, const float* __restrict__ fc2b,
    float* __restrict__ out)
{
  __shared__ float lsA[64 * 161];   // ws tile (stride 161) / Fn tile (stride 132)
  __shared__ float lsE[1280];       // B chunk 8x132 (skewed) / fc2_w (128x10)
  __shared__ int ridx[NEST];

  const int f = blockIdx.y;
  const int b0 = blockIdx.x * 64;
  const int tid = threadIdx.x;
  const int ty = tid >> 4, tx = tid & 15;
  const int srow = tid >> 5;            // staging row 0..7
  const int sg = tid & 31;              // staging float4-group 0..31
  const int sgp = (sg ^ (sg >> 2)) * 4; // skewed store offset (floats)

  if (tid < NEST) ridx[tid] = swr[f * NEST + tid];

  // stage ws tile (bf16 -> f32), rows = b, stride 161 breaks bank aliasing
  for (int i = tid; i < 64 * 80; i += 256) {
    int r = i / 80, e2 = i - r * 80;
    const uint32_t* p = (const uint32_t*)(wsb + ((size_t)(b0 + r) * NFOR + f) * NEST);
    uint32_t u = p[e2];
    union { uint32_t u; float f; } lo, hi;
    lo.u = u << 16; hi.u = u & 0xffff0000u;
    lsA[r * 161 + 2 * e2]     = lo.f;
    lsA[r * 161 + 2 * e2 + 1] = hi.f;
  }
  __syncthreads();

  float acc[4][8];
#pragma unroll
  for (int i = 0; i < 4; i++)
#pragma unroll
    for (int j = 0; j < 8; j++) acc[i][j] = 0.f;

  const int g0 = 2 * tx, g1 = 2 * tx + 1;
  const int p0 = (g0 ^ (g0 >> 2)) * 4;  // skewed read offsets
  const int p1 = (g1 ^ (g1 >> 2)) * 4;

  // ---- GEMM1: F = ws[64x160] @ Ep[160x128] ----
  for (int kc = 0; kc < NEST; kc += 8) {
    const int er = ridx[kc + srow];
    const float4 ev = *(const float4*)(E + (size_t)er * NHID + sg * 4);
    __syncthreads();                       // prev chunk consumed
    *(float4*)&lsE[srow * 132 + sgp] = ev;
    __syncthreads();
#pragma unroll
    for (int kk = 0; kk < 8; kk++) {
      float aa[4];
#pragma unroll
      for (int i = 0; i < 4; i++) aa[i] = lsA[(ty * 4 + i) * 161 + kc + kk];
      float4 bv0 = *(const float4*)&lsE[kk * 132 + p0];
      float4 bv1 = *(const float4*)&lsE[kk * 132 + p1];
      float bb[8] = {bv0.x, bv0.y, bv0.z, bv0.w, bv1.x, bv1.y, bv1.z, bv1.w};
#pragma unroll
      for (int i = 0; i < 4; i++)
#pragma unroll
        for (int j = 0; j < 8; j++) acc[i][j] = fmaf(aa[i], bb[j], acc[i][j]);
    }
  }
  __syncthreads();

  // ---- LN1 (rows owned by 16 consecutive lanes -> shfl_xor reduce) ----
  {
    const float4 a0 = *(const float4*)(ln1w + tx * 8);
    const float4 a1 = *(const float4*)(ln1w + tx * 8 + 4);
    const float4 c0 = *(const float4*)(ln1b + tx * 8);
    const float4 c1 = *(const float4*)(ln1b + tx * 8 + 4);
    float lw[8] = {a0.x, a0.y, a0.z, a0.w, a1.x, a1.y, a1.z, a1.w};
    float lb[8] = {c0.x, c0.y, c0.z, c0.w, c1.x, c1.y, c1.z, c1.w};
#pragma unroll
    for (int i = 0; i < 4; i++) {
      float s1 = 0.f, s2 = 0.f;
#pragma unroll
      for (int j = 0; j < 8; j++) { s1 += acc[i][j]; s2 += acc[i][j] * acc[i][j]; }
#pragma unroll
      for (int off = 1; off < 16; off <<= 1) {
        s1 += __shfl_xor(s1, off);
        s2 += __shfl_xor(s2, off);
      }
      float mu = s1 * (1.f / 128.f);
      float var = fmaxf(s2 * (1.f / 128.f) - mu * mu, 0.f);
      float rs = rsqrtf(var + GEPS);
#pragma unroll
      for (int j = 0; j < 8; j++)
        acc[i][j] = (acc[i][j] - mu) * rs * lw[j] + lb[j];
    }
  }
  // write Fn tile (stride 132) into lsA region
#pragma unroll
  for (int i = 0; i < 4; i++) {
    float4 v0 = make_float4(acc[i][0], acc[i][1], acc[i][2], acc[i][3]);
    float4 v1 = make_float4(acc[i][4], acc[i][5], acc[i][6], acc[i][7]);
    *(float4*)&lsA[(ty * 4 + i) * 132 + tx * 8]     = v0;
    *(float4*)&lsA[(ty * 4 + i) * 132 + tx * 8 + 4] = v1;
  }
  __syncthreads();

  // ---- GEMM2: H = Fn[64x128] @ fc1_w[128x128] ----
#pragma unroll
  for (int i = 0; i < 4; i++)
#pragma unroll
    for (int j = 0; j < 8; j++) acc[i][j] = 0.f;

  for (int kc = 0; kc < NHID; kc += 8) {
    const float4 fv = *(const float4*)(fc1w + (size_t)(kc + srow) * NHID + sg * 4);
    __syncthreads();
    *(float4*)&lsE[srow * 132 + sgp] = fv;
    __syncthreads();
#pragma unroll
    for (int kk = 0; kk < 8; kk++) {
      float aa[4];
#pragma unroll
      for (int i = 0; i < 4; i++) aa[i] = lsA[(ty * 4 + i) * 132 + kc + kk];
      float4 bv0 = *(const float4*)&lsE[kk * 132 + p0];
      float4 bv1 = *(const float4*)&lsE[kk * 132 + p1];
      float bb[8] = {bv0.x, bv0.y, bv0.z, bv0.w, bv1.x, bv1.y, bv1.z, bv1.w};
#pragma unroll
      for (int i = 0; i < 4; i++)
#pragma unroll
        for (int j = 0; j < 8; j++) acc[i][j] = fmaf(aa[i], bb[j], acc[i][j]);
    }
  }
  __syncthreads();   // all reads of lsA/lsE done; safe to overwrite below

  // ---- bias + ReLU + LN2 ----
  {
    const float4 f0 = *(const float4*)(fc1b + tx * 8);
    const float4 f1 = *(const float4*)(fc1b + tx * 8 + 4);
    float fb[8] = {f0.x, f0.y, f0.z, f0.w, f1.x, f1.y, f1.z, f1.w};
    const float4 a0 = *(const float4*)(ln2w + tx * 8);
    const float4 a1 = *(const float4*)(ln2w + tx * 8 + 4);
    const float4 c0 = *(const float4*)(ln2b + tx * 8);
    const float4 c1 = *(const float4*)(ln2b + tx * 8 + 4);
    float lw[8] = {a0.x, a0.y, a0.z, a0.w, a1.x, a1.y, a1.z, a1.w};
    float lb[8] = {c0.x, c0.y, c0.z, c0.w, c1.x, c1.y, c1.z, c1.w};
#pragma unroll
    for (int i = 0; i < 4; i++) {
#pragma unroll
      for (int j = 0; j < 8; j++) acc[i][j] = fmaxf(acc[i][j] + fb[j], 0.f);
      float s1 = 0.f, s2 = 0.f;
#pragma unroll
      for (int j = 0; j < 8; j++) { s1 += acc[i][j]; s2 += acc[i][j] * acc[i][j]; }
#pragma unroll
      for (int off = 1; off < 16; off <<= 1) {
        s1 += __shfl_xor(s1, off);
        s2 += __shfl_xor(s2, off);
      }
      float mu = s1 * (1.f / 128.f);
      float var = fmaxf(s2 * (1.f / 128.f) - mu * mu, 0.f);
      float rs = rsqrtf(var + GEPS);
#pragma unroll
      for (int j = 0; j < 8; j++)
        acc[i][j] = (acc[i][j] - mu) * rs * lw[j] + lb[j];
    }
  }
  // write Fn2 tile (stride 132) + stage fc2_w
#pragma unroll
  for (int i = 0; i < 4; i++) {
    float4 v0 = make_float4(acc[i][0], acc[i][1], acc[i][2], acc[i][3]);
    float4 v1 = make_float4(acc[i][4], acc[i][5], acc[i][6], acc[i][7]);
    *(float4*)&lsA[(ty * 4 + i) * 132 + tx * 8]     = v0;
    *(float4*)&lsA[(ty * 4 + i) * 132 + tx * 8 + 4] = v1;
  }
  for (int i = tid; i < NHID * NCLS; i += 256) lsE[i] = fc2w[i];
  __syncthreads();

  // ---- fc2 + mean over forests (atomic) ----
  for (int o = tid; o < 64 * NCLS; o += 256) {
    int row = o / NCLS, cls = o - row * NCLS;
    const float* fr = &lsA[row * 132];
    float a = fc2b[cls];
    for (int k = 0; k < NHID; k++) a = fmaf(fr[k], lsE[k * NCLS + cls], a);
    atomicAdd(&out[(size_t)(b0 + row) * NCLS + cls], a * 0.01f);
  }
}

// ---------------------------------------------------------------------------
extern "C" void kernel_launch(void* const* d_in, const int* in_sizes, int n_in,
                              void* d_out, int out_size, void* d_ws, size_t ws_size,
                              hipStream_t stream)
{
  (void)in_sizes; (void)n_in; (void)ws_size;
  const float* x    = (const float*)d_in[0];
  const float* w1   = (const float*)d_in[1];
  const float* b1   = (const float*)d_in[2];
  const int*   perm = (const int*)d_in[3];
  const float* gn1w = (const float*)d_in[4];
  const float* gn1b = (const float*)d_in[5];
  const float* c2w  = (const float*)d_in[6];
  const float* c2b  = (const float*)d_in[7];
  const float* gn2w = (const float*)d_in[8];
  const float* gn2b = (const float*)d_in[9];
  const float* c3w  = (const float*)d_in[10];
  const float* c3b  = (const float*)d_in[11];
  const int*   swr  = (const int*)d_in[12];
  const float* E    = (const float*)d_in[13];
  const float* ln1w = (const float*)d_in[14];
  const float* ln1b = (const float*)d_in[15];
  const float* fc1w = (const float*)d_in[16];
  const float* fc1b = (const float*)d_in[17];
  const float* ln2w = (const float*)d_in[18];
  const float* ln2b = (const float*)d_in[19];
  const float* fc2w = (const float*)d_in[20];
  const float* fc2b = (const float*)d_in[21];
  float* out = (float*)d_out;

  float* wbuf = (float*)d_ws;                                       // 26.2 MB
  __hip_bfloat16* wsbuf =
      (__hip_bfloat16*)((char*)d_ws + (size_t)NB * NRODT * sizeof(float)); // 131 MB

  hipMemsetAsync(d_out, 0, (size_t)out_size * sizeof(float), stream);
  k1_w<<<NB / 8, 256, 0, stream>>>(x, w1, b1, perm, gn1w, gn1b, c2w, c2b,
                                   gn2w, gn2b, c3w, c3b, wbuf);
  k2_softmax<<<NB, 256, 0, stream>>>(wbuf, swr, wsbuf);
  dim3 g3(NB / 64, NFOR);
  k3_fused<<<g3, 256, 0, stream>>>(wsbuf, swr, E, ln1w, ln1b, fc1w, fc1b,
                                   ln2w, ln2b, fc2w, fc2b, out);
}

// Round 2
// 410.928 us; speedup vs baseline: 1.5877x; 1.5877x over previous
//
#include <hip/hip_runtime.h>
#include <hip/hip_bf16.h>
#include <stdint.h>

#define NB 4096
#define NCOL 100
#define NCOND 64
#define NTOTAL 6400
#define NRODT 1600
#define NEST 160
#define NFOR 100
#define NHID 128
#define NCLS 10
#define GEPS 1e-5f

typedef __attribute__((ext_vector_type(8))) short short8;
typedef __attribute__((ext_vector_type(4))) float floatx4;

__device__ __forceinline__ unsigned short f2bf(float x) {
  union { float f; unsigned u; } v; v.f = x;
  unsigned r = v.u + 0x7fffu + ((v.u >> 16) & 1u);   // RNE
  return (unsigned short)(r >> 16);
}

// ---------------------------------------------------------------------------
// K1: fused ConditionGeneration + perm + phi_2 -> w logits [b][g] f32.
// 32 samples per block: per-group weights fetched once per 32 b.
// ---------------------------------------------------------------------------
__global__ __launch_bounds__(256) void k1_w(
    const float* __restrict__ x, const float* __restrict__ w1,
    const float* __restrict__ b1, const int* __restrict__ perm,
    const float* __restrict__ gn1w, const float* __restrict__ gn1b,
    const float* __restrict__ c2w, const float* __restrict__ c2b,
    const float* __restrict__ gn2w, const float* __restrict__ gn2b,
    const float* __restrict__ c3w, const float* __restrict__ c3b,
    float* __restrict__ wout)
{
  __shared__ float xl[32 * NCOL];
  const int b0 = blockIdx.x * 32;
  for (int i = threadIdx.x; i < 32 * NCOL; i += 256)
    xl[i] = x[(size_t)b0 * NCOL + i];
  __syncthreads();

  for (int g = threadIdx.x; g < NRODT; g += 256) {
    const int4 p4 = *(const int4*)(perm + 4 * g);
    const int pv[4] = {p4.x, p4.y, p4.z, p4.w};
    float w1v[4], b1v[4];
    int pc[4];
#pragma unroll
    for (int i = 0; i < 4; i++) {
      unsigned p = (unsigned)pv[i];
      unsigned j = p / 100u;
      unsigned cc = p - j * 100u;
      pc[i] = (int)cc;
      w1v[i] = w1[cc * NCOND + j];
      b1v[i] = b1[cc * NCOND + j];
    }
    const float4 g1w = *(const float4*)(gn1w + 4 * g);
    const float4 g1b = *(const float4*)(gn1b + 4 * g);
    const float4 cw0 = *(const float4*)(c2w + 16 * g);
    const float4 cw1 = *(const float4*)(c2w + 16 * g + 4);
    const float4 cw2 = *(const float4*)(c2w + 16 * g + 8);
    const float4 cw3 = *(const float4*)(c2w + 16 * g + 12);
    const float4 cbv = *(const float4*)(c2b + 4 * g);
    const float4 g2w = *(const float4*)(gn2w + 4 * g);
    const float4 g2b = *(const float4*)(gn2b + 4 * g);
    const float4 c3v = *(const float4*)(c3w + 4 * g);
    const float c3bv = c3b[g];

    for (int bb = 0; bb < 32; bb++) {
      float O[4];
#pragma unroll
      for (int i = 0; i < 4; i++) {
        float a = xl[bb * NCOL + pc[i]] * w1v[i] + b1v[i];
        O[i] = 1.0f / (1.0f + __expf(-a));
      }
      float mu = 0.25f * (O[0] + O[1] + O[2] + O[3]);
      float d[4], var = 0.f;
#pragma unroll
      for (int i = 0; i < 4; i++) { d[i] = O[i] - mu; var += d[i] * d[i]; }
      float rs = rsqrtf(0.25f * var + GEPS);
      float xn0 = d[0] * rs * g1w.x + g1b.x;
      float xn1 = d[1] * rs * g1w.y + g1b.y;
      float xn2 = d[2] * rs * g1w.z + g1b.z;
      float xn3 = d[3] * rs * g1w.w + g1b.w;
      float h[4];
      h[0] = xn0*cw0.x + xn1*cw1.x + xn2*cw2.x + xn3*cw3.x + cbv.x;
      h[1] = xn0*cw0.y + xn1*cw1.y + xn2*cw2.y + xn3*cw3.y + cbv.y;
      h[2] = xn0*cw0.z + xn1*cw1.z + xn2*cw2.z + xn3*cw3.z + cbv.z;
      h[3] = xn0*cw0.w + xn1*cw1.w + xn2*cw2.w + xn3*cw3.w + cbv.w;
#pragma unroll
      for (int i = 0; i < 4; i++) h[i] = fmaxf(h[i], 0.f);
      float mu2 = 0.25f * (h[0] + h[1] + h[2] + h[3]);
      float e[4], var2 = 0.f;
#pragma unroll
      for (int i = 0; i < 4; i++) { e[i] = h[i] - mu2; var2 += e[i] * e[i]; }
      float rs2 = rsqrtf(0.25f * var2 + GEPS);
      float hn0 = e[0] * rs2 * g2w.x + g2b.x;
      float hn1 = e[1] * rs2 * g2w.y + g2b.y;
      float hn2 = e[2] * rs2 * g2w.z + g2b.z;
      float hn3 = e[3] * rs2 * g2w.w + g2b.w;
      float wv = hn0*c3v.x + hn1*c3v.y + hn2*c3v.z + hn3*c3v.w + c3bv;
      wout[(size_t)(b0 + bb) * NRODT + g] = wv;
    }
  }
}

// ---------------------------------------------------------------------------
// K2: per (b,f) gather + softmax -> ws bf16, f-major [f][b][160]
// ---------------------------------------------------------------------------
__global__ __launch_bounds__(256) void k2_softmax(
    const float* __restrict__ wv, const int* __restrict__ swr,
    __hip_bfloat16* __restrict__ wsout)
{
  __shared__ float wl[NRODT];
  const int b = blockIdx.x;
  for (int i = threadIdx.x; i < NRODT; i += 256) wl[i] = wv[(size_t)b * NRODT + i];
  __syncthreads();

  const int wave = threadIdx.x >> 6, lane = threadIdx.x & 63;
  for (int f = wave; f < NFOR; f += 4) {
    const int* sw = swr + f * NEST;
    float v0 = wl[sw[lane]];
    float v1 = wl[sw[lane + 64]];
    float v2 = (lane < 32) ? wl[sw[lane + 128]] : -1e30f;
    float m = fmaxf(fmaxf(v0, v1), v2);
#pragma unroll
    for (int off = 32; off; off >>= 1) m = fmaxf(m, __shfl_xor(m, off));
    float e0 = __expf(v0 - m), e1 = __expf(v1 - m);
    float e2 = (lane < 32) ? __expf(v2 - m) : 0.0f;
    float s = e0 + e1 + e2;
#pragma unroll
    for (int off = 32; off; off >>= 1) s += __shfl_xor(s, off);
    float inv = 1.0f / s;
    __hip_bfloat16* o = wsout + ((size_t)f * NB + b) * NEST;
    o[lane]      = __float2bfloat16(e0 * inv);
    o[lane + 64] = __float2bfloat16(e1 * inv);
    if (lane < 32) o[lane + 128] = __float2bfloat16(e2 * inv);
  }
}

// ---------------------------------------------------------------------------
// K0: prep (runs AFTER k2; overlays the w-logits buffer).
//  blocks 0..99 : EpT[f][h][e] bf16 = E[swr[f][e]][h]   (gather+transpose)
//  block  100   : fc1wT[o][k] bf16 = fc1w[k][o]
//  block  101   : fc2wT[n][k] bf16 = n<10 ? fc2w[k][n] : 0   (16 padded cols)
// ---------------------------------------------------------------------------
__global__ __launch_bounds__(256) void k0_prep(
    const float* __restrict__ E, const int* __restrict__ swr,
    const float* __restrict__ fc1w, const float* __restrict__ fc2w,
    unsigned short* __restrict__ EpT, unsigned short* __restrict__ fc1wT,
    unsigned short* __restrict__ fc2wT)
{
  __shared__ __align__(16) char smraw[80 * 133 * 4];
  float* G = (float*)smraw;
  __shared__ int ridx[NEST];
  const int tid = threadIdx.x;
  const int blk = blockIdx.x;

  if (blk < NFOR) {
    if (tid < NEST) ridx[tid] = swr[blk * NEST + tid];
    __syncthreads();
    for (int half = 0; half < 2; half++) {
      for (int cidx = tid; cidx < 2560; cidx += 256) {   // 80 rows x 32 f4
        int e = cidx >> 5, ch = cidx & 31;
        float4 v = *(const float4*)(E + (size_t)ridx[half * 80 + e] * NHID + ch * 4);
        float* gp = G + e * 133 + ch * 4;
        gp[0] = v.x; gp[1] = v.y; gp[2] = v.z; gp[3] = v.w;
      }
      __syncthreads();
      int h = tid >> 1, part = tid & 1;
      size_t ob = (size_t)blk * 20480 + (size_t)h * 160 + half * 80 + part * 40;
      for (int j = 0; j < 40; j += 2) {
        int e = part * 40 + j;
        unsigned lo = f2bf(G[e * 133 + h]);
        unsigned hi = f2bf(G[(e + 1) * 133 + h]);
        *(unsigned*)(EpT + ob + j) = lo | (hi << 16);
      }
      __syncthreads();
    }
  } else if (blk == NFOR) {
    for (int half = 0; half < 2; half++) {
      for (int cidx = tid; cidx < 2048; cidx += 256) {   // 64 rows x 32 f4
        int k = cidx >> 5, ch = cidx & 31;
        float4 v = *(const float4*)(fc1w + (size_t)(half * 64 + k) * NHID + ch * 4);
        float* gp = G + k * 133 + ch * 4;
        gp[0] = v.x; gp[1] = v.y; gp[2] = v.z; gp[3] = v.w;
      }
      __syncthreads();
      int o = tid >> 1, part = tid & 1;
      for (int j = 0; j < 32; j += 2) {
        int k = part * 32 + j;
        unsigned lo = f2bf(G[k * 133 + o]);
        unsigned hi = f2bf(G[(k + 1) * 133 + o]);
        *(unsigned*)(fc1wT + o * NHID + half * 64 + k) = lo | (hi << 16);
      }
      __syncthreads();
    }
  } else {
    for (int cidx = tid; cidx < 2048; cidx += 256) {
      int n = cidx >> 7, k = cidx & 127;
      float v = (n < NCLS) ? fc2w[k * NCLS + n] : 0.f;
      fc2wT[n * NHID + k] = f2bf(v);
    }
  }
}

// ---------------------------------------------------------------------------
// K3: MFMA-fused  F=ws@Ep -> LN1 -> fc1 -> ReLU+LN2 -> fc2 -> mean.
// Block = (64 b, forest f). 4 waves, each owns a 16-row strip x 128 cols.
// lsA stride 168 bf16: frag b128 reads land 8 lanes/4-bank-group = exactly
// the conflict-free minimum for wave64.
// ---------------------------------------------------------------------------
__global__ __launch_bounds__(256, 2) void k3_mfma(
    const unsigned short* __restrict__ wsb,    // [f][B][160] bf16
    const unsigned short* __restrict__ EpT,    // [f][128][160] bf16
    const unsigned short* __restrict__ fc1wTb, // [128][128] bf16
    const unsigned short* __restrict__ fc2wTb, // [16][128] bf16
    const float* __restrict__ ln1w, const float* __restrict__ ln1b,
    const float* __restrict__ fc1b,
    const float* __restrict__ ln2w, const float* __restrict__ ln2b,
    const float* __restrict__ fc2b,
    float* __restrict__ out)
{
  __shared__ unsigned short lsA[64 * 168];    // 21504 B
  __shared__ unsigned short lsB[128 * 168];   // 43008 B

  const int tid = threadIdx.x;
  const int b0 = blockIdx.x * 64;
  const int f  = blockIdx.y;
  const int lane = tid & 63, wv = tid >> 6;
  const int c = lane & 15, q = lane >> 4;

  // ---- stage A (ws tile, already bf16 row-major) + B (EpT[f]) ----
  {
    const uint4* srcA = (const uint4*)(wsb + ((size_t)f * NB + b0) * NEST);
    for (int i = tid; i < 1280; i += 256) {          // 64 x 20 uint4
      int r = i / 20, ch = i - r * 20;
      *(uint4*)(lsA + r * 168 + ch * 8) = srcA[i];
    }
    const uint4* srcB = (const uint4*)(EpT + (size_t)f * 20480);
    for (int i = tid; i < 2560; i += 256) {          // 128 x 20 uint4
      int r = i / 20, ch = i - r * 20;
      *(uint4*)(lsB + r * 168 + ch * 8) = srcB[i];
    }
  }
  __syncthreads();

  const unsigned short* pa = lsA + (wv * 16 + c) * 168 + q * 8;
  const unsigned short* pb = lsB + c * 168 + q * 8;

  floatx4 acc[8];
#pragma unroll
  for (int n = 0; n < 8; n++) acc[n] = (floatx4){0.f, 0.f, 0.f, 0.f};

  // ---- GEMM1: F = ws[64x160] @ Ep[160x128] ----
#pragma unroll
  for (int kc = 0; kc < NEST; kc += 32) {
    short8 a = *(const short8*)(pa + kc);
#pragma unroll
    for (int n = 0; n < 8; n++) {
      short8 b = *(const short8*)(pb + n * 16 * 168 + kc);
      acc[n] = __builtin_amdgcn_mfma_f32_16x16x32_bf16(a, b, acc[n], 0, 0, 0);
    }
  }

  // ---- LN1 (C-layout: row = 4q+r, cols 16n+c; reduce over 16 lanes) ----
  {
    float lw[8], lb[8];
#pragma unroll
    for (int n = 0; n < 8; n++) { lw[n] = ln1w[n * 16 + c]; lb[n] = ln1b[n * 16 + c]; }
#pragma unroll
    for (int r = 0; r < 4; r++) {
      float s1 = 0.f, s2 = 0.f;
#pragma unroll
      for (int n = 0; n < 8; n++) { float v = acc[n][r]; s1 += v; s2 += v * v; }
#pragma unroll
      for (int off = 1; off < 16; off <<= 1) {
        s1 += __shfl_xor(s1, off); s2 += __shfl_xor(s2, off);
      }
      float mu = s1 * (1.f / 128.f);
      float var = fmaxf(s2 * (1.f / 128.f) - mu * mu, 0.f);
      float rs = rsqrtf(var + GEPS);
#pragma unroll
      for (int n = 0; n < 8; n++)
        acc[n][r] = (acc[n][r] - mu) * rs * lw[n] + lb[n];
    }
  }
  __syncthreads();   // GEMM1 LDS reads complete; safe to overwrite lsA/lsB

  // ---- Fn -> lsA (A-layout bf16); fc1wT -> lsB ----
#pragma unroll
  for (int r = 0; r < 4; r++)
#pragma unroll
    for (int n = 0; n < 8; n++)
      lsA[(wv * 16 + q * 4 + r) * 168 + n * 16 + c] = f2bf(acc[n][r]);
  {
    const uint4* srcW = (const uint4*)fc1wTb;
    for (int i = tid; i < 2048; i += 256) {          // 128 x 16 uint4
      int r = i >> 4, ch = i & 15;
      *(uint4*)(lsB + r * 168 + ch * 8) = srcW[i];
    }
  }
  __syncthreads();

  // ---- GEMM2: H = Fn[64x128] @ fc1w[128x128] ----
#pragma unroll
  for (int n = 0; n < 8; n++) acc[n] = (floatx4){0.f, 0.f, 0.f, 0.f};
#pragma unroll
  for (int kc = 0; kc < NHID; kc += 32) {
    short8 a = *(const short8*)(pa + kc);
#pragma unroll
    for (int n = 0; n < 8; n++) {
      short8 b = *(const short8*)(pb + n * 16 * 168 + kc);
      acc[n] = __builtin_amdgcn_mfma_f32_16x16x32_bf16(a, b, acc[n], 0, 0, 0);
    }
  }

  // ---- bias + ReLU + LN2 ----
  {
    float fb[8], lw[8], lb[8];
#pragma unroll
    for (int n = 0; n < 8; n++) {
      fb[n] = fc1b[n * 16 + c];
      lw[n] = ln2w[n * 16 + c]; lb[n] = ln2b[n * 16 + c];
    }
#pragma unroll
    for (int r = 0; r < 4; r++) {
#pragma unroll
      for (int n = 0; n < 8; n++) acc[n][r] = fmaxf(acc[n][r] + fb[n], 0.f);
      float s1 = 0.f, s2 = 0.f;
#pragma unroll
      for (int n = 0; n < 8; n++) { float v = acc[n][r]; s1 += v; s2 += v * v; }
#pragma unroll
      for (int off = 1; off < 16; off <<= 1) {
        s1 += __shfl_xor(s1, off); s2 += __shfl_xor(s2, off);
      }
      float mu = s1 * (1.f / 128.f);
      float var = fmaxf(s2 * (1.f / 128.f) - mu * mu, 0.f);
      float rs = rsqrtf(var + GEPS);
#pragma unroll
      for (int n = 0; n < 8; n++)
        acc[n][r] = (acc[n][r] - mu) * rs * lw[n] + lb[n];
    }
  }
  __syncthreads();   // GEMM2 LDS reads complete

  // ---- H2 -> lsA (A-layout bf16); fc2wT -> lsB ----
#pragma unroll
  for (int r = 0; r < 4; r++)
#pragma unroll
    for (int n = 0; n < 8; n++)
      lsA[(wv * 16 + q * 4 + r) * 168 + n * 16 + c] = f2bf(acc[n][r]);
  if (tid < 256) {
    int r = tid >> 4, ch = tid & 15;                 // 16 x 16 uint4
    *(uint4*)(lsB + r * 168 + ch * 8) = ((const uint4*)fc2wTb)[tid];
  }
  __syncthreads();

  // ---- fc2: one 16-col MFMA tile per wave strip + mean-atomic ----
  floatx4 o4 = (floatx4){0.f, 0.f, 0.f, 0.f};
#pragma unroll
  for (int kc = 0; kc < NHID; kc += 32) {
    short8 a = *(const short8*)(pa + kc);
    short8 b = *(const short8*)(pb + kc);
    o4 = __builtin_amdgcn_mfma_f32_16x16x32_bf16(a, b, o4, 0, 0, 0);
  }
  if (c < NCLS) {
    float bias = fc2b[c];
#pragma unroll
    for (int r = 0; r < 4; r++)
      atomicAdd(out + (size_t)(b0 + wv * 16 + q * 4 + r) * NCLS + c,
                (o4[r] + bias) * 0.01f);
  }
}

// ---------------------------------------------------------------------------
extern "C" void kernel_launch(void* const* d_in, const int* in_sizes, int n_in,
                              void* d_out, int out_size, void* d_ws, size_t ws_size,
                              hipStream_t stream)
{
  (void)in_sizes; (void)n_in; (void)ws_size;
  const float* x    = (const float*)d_in[0];
  const float* w1   = (const float*)d_in[1];
  const float* b1   = (const float*)d_in[2];
  const int*   perm = (const int*)d_in[3];
  const float* gn1w = (const float*)d_in[4];
  const float* gn1b = (const float*)d_in[5];
  const float* c2w  = (const float*)d_in[6];
  const float* c2b  = (const float*)d_in[7];
  const float* gn2w = (const float*)d_in[8];
  const float* gn2b = (const float*)d_in[9];
  const float* c3w  = (const float*)d_in[10];
  const float* c3b  = (const float*)d_in[11];
  const int*   swr  = (const int*)d_in[12];
  const float* E    = (const float*)d_in[13];
  const float* ln1w = (const float*)d_in[14];
  const float* ln1b = (const float*)d_in[15];
  const float* fc1w = (const float*)d_in[16];
  const float* fc1b = (const float*)d_in[17];
  const float* ln2w = (const float*)d_in[18];
  const float* ln2b = (const float*)d_in[19];
  const float* fc2w = (const float*)d_in[20];
  const float* fc2b = (const float*)d_in[21];
  float* out = (float*)d_out;

  // workspace layout:
  //   [0, 26.2MB)  : w logits f32 (k1 -> k2), then overlaid by k0 outputs:
  //                  EpT 4,096,000 B | fc1wT 32,768 B | fc2wT 4,096 B
  //   [26.2MB, +131MB) : ws bf16 [f][B][160]
  float* wbuf = (float*)d_ws;
  unsigned short* wsbuf  = (unsigned short*)((char*)d_ws + (size_t)NB * NRODT * 4);
  unsigned short* EpTb   = (unsigned short*)d_ws;
  unsigned short* fc1wTb = (unsigned short*)((char*)d_ws + 4096000);
  unsigned short* fc2wTb = (unsigned short*)((char*)d_ws + 4096000 + 32768);

  hipMemsetAsync(d_out, 0, (size_t)out_size * sizeof(float), stream);
  k1_w<<<NB / 32, 256, 0, stream>>>(x, w1, b1, perm, gn1w, gn1b, c2w, c2b,
                                    gn2w, gn2b, c3w, c3b, wbuf);
  k2_softmax<<<NB, 256, 0, stream>>>(wbuf, swr, (__hip_bfloat16*)wsbuf);
  // k0 AFTER k2: it overwrites the w-logits region
  k0_prep<<<NFOR + 2, 256, 0, stream>>>(E, swr, fc1w, fc2w, EpTb, fc1wTb, fc2wTb);
  dim3 g3(NB / 64, NFOR);
  k3_mfma<<<g3, 256, 0, stream>>>(wsbuf, EpTb, fc1wTb, fc2wTb,
                                  ln1w, ln1b, fc1b, ln2w, ln2b, fc2b, out);
}

// Round 4
// 314.301 us; speedup vs baseline: 2.0758x; 1.3074x over previous
//
#include <hip/hip_runtime.h>
#include <hip/hip_bf16.h>
#include <stdint.h>

#define NB 4096
#define NCOL 100
#define NCOND 64
#define NTOTAL 6400
#define NRODT 1600
#define NEST 160
#define NFOR 100
#define NHID 128
#define NCLS 10
#define GEPS 1e-5f

typedef __attribute__((ext_vector_type(8))) short short8;
typedef __attribute__((ext_vector_type(4))) float floatx4;

__device__ __forceinline__ unsigned short f2bf(float x) {
  union { float f; unsigned u; } v; v.f = x;
  unsigned r = v.u + 0x7fffu + ((v.u >> 16) & 1u);   // RNE
  return (unsigned short)(r >> 16);
}

// ---------------------------------------------------------------------------
// K1: fused ConditionGeneration + perm + phi_2 -> w logits [b][g] f32.
// grid (NB/8, 4): 8 samples x 400-group chunk per block = 2048 blocks.
// ---------------------------------------------------------------------------
__global__ __launch_bounds__(256) void k1_w(
    const float* __restrict__ x, const float* __restrict__ w1,
    const float* __restrict__ b1, const int* __restrict__ perm,
    const float* __restrict__ gn1w, const float* __restrict__ gn1b,
    const float* __restrict__ c2w, const float* __restrict__ c2b,
    const float* __restrict__ gn2w, const float* __restrict__ gn2b,
    const float* __restrict__ c3w, const float* __restrict__ c3b,
    float* __restrict__ wout)
{
  __shared__ float xl[8 * NCOL];
  const int b0 = blockIdx.x * 8;
  const int g0 = blockIdx.y * 400;
  for (int i = threadIdx.x; i < 8 * NCOL; i += 256)
    xl[i] = x[(size_t)b0 * NCOL + i];
  __syncthreads();

  for (int g = g0 + threadIdx.x; g < g0 + 400; g += 256) {
    const int4 p4 = *(const int4*)(perm + 4 * g);
    const int pv[4] = {p4.x, p4.y, p4.z, p4.w};
    float w1v[4], b1v[4];
    int pc[4];
#pragma unroll
    for (int i = 0; i < 4; i++) {
      unsigned p = (unsigned)pv[i];
      unsigned j = p / 100u;
      unsigned cc = p - j * 100u;
      pc[i] = (int)cc;
      w1v[i] = w1[cc * NCOND + j];
      b1v[i] = b1[cc * NCOND + j];
    }
    const float4 g1w = *(const float4*)(gn1w + 4 * g);
    const float4 g1b = *(const float4*)(gn1b + 4 * g);
    const float4 cw0 = *(const float4*)(c2w + 16 * g);
    const float4 cw1 = *(const float4*)(c2w + 16 * g + 4);
    const float4 cw2 = *(const float4*)(c2w + 16 * g + 8);
    const float4 cw3 = *(const float4*)(c2w + 16 * g + 12);
    const float4 cbv = *(const float4*)(c2b + 4 * g);
    const float4 g2w = *(const float4*)(gn2w + 4 * g);
    const float4 g2b = *(const float4*)(gn2b + 4 * g);
    const float4 c3v = *(const float4*)(c3w + 4 * g);
    const float c3bv = c3b[g];

    for (int bb = 0; bb < 8; bb++) {
      float O[4];
#pragma unroll
      for (int i = 0; i < 4; i++) {
        float a = xl[bb * NCOL + pc[i]] * w1v[i] + b1v[i];
        O[i] = 1.0f / (1.0f + __expf(-a));
      }
      float mu = 0.25f * (O[0] + O[1] + O[2] + O[3]);
      float d[4], var = 0.f;
#pragma unroll
      for (int i = 0; i < 4; i++) { d[i] = O[i] - mu; var += d[i] * d[i]; }
      float rs = rsqrtf(0.25f * var + GEPS);
      float xn0 = d[0] * rs * g1w.x + g1b.x;
      float xn1 = d[1] * rs * g1w.y + g1b.y;
      float xn2 = d[2] * rs * g1w.z + g1b.z;
      float xn3 = d[3] * rs * g1w.w + g1b.w;
      float h[4];
      h[0] = xn0*cw0.x + xn1*cw1.x + xn2*cw2.x + xn3*cw3.x + cbv.x;
      h[1] = xn0*cw0.y + xn1*cw1.y + xn2*cw2.y + xn3*cw3.y + cbv.y;
      h[2] = xn0*cw0.z + xn1*cw1.z + xn2*cw2.z + xn3*cw3.z + cbv.z;
      h[3] = xn0*cw0.w + xn1*cw1.w + xn2*cw2.w + xn3*cw3.w + cbv.w;
#pragma unroll
      for (int i = 0; i < 4; i++) h[i] = fmaxf(h[i], 0.f);
      float mu2 = 0.25f * (h[0] + h[1] + h[2] + h[3]);
      float e[4], var2 = 0.f;
#pragma unroll
      for (int i = 0; i < 4; i++) { e[i] = h[i] - mu2; var2 += e[i] * e[i]; }
      float rs2 = rsqrtf(0.25f * var2 + GEPS);
      float hn0 = e[0] * rs2 * g2w.x + g2b.x;
      float hn1 = e[1] * rs2 * g2w.y + g2b.y;
      float hn2 = e[2] * rs2 * g2w.z + g2b.z;
      float hn3 = e[3] * rs2 * g2w.w + g2b.w;
      float wv = hn0*c3v.x + hn1*c3v.y + hn2*c3v.z + hn3*c3v.w + c3bv;
      wout[(size_t)(b0 + bb) * NRODT + g] = wv;
    }
  }
}

// ---------------------------------------------------------------------------
// K2: per (b,f) gather + softmax -> ws bf16, f-major [f][b][160]
// ---------------------------------------------------------------------------
__global__ __launch_bounds__(256) void k2_softmax(
    const float* __restrict__ wv, const int* __restrict__ swr,
    __hip_bfloat16* __restrict__ wsout)
{
  __shared__ float wl[NRODT];
  const int b = blockIdx.x;
  for (int i = threadIdx.x; i < NRODT; i += 256) wl[i] = wv[(size_t)b * NRODT + i];
  __syncthreads();

  const int wave = threadIdx.x >> 6, lane = threadIdx.x & 63;
  for (int f = wave; f < NFOR; f += 4) {
    const int* sw = swr + f * NEST;
    float v0 = wl[sw[lane]];
    float v1 = wl[sw[lane + 64]];
    float v2 = (lane < 32) ? wl[sw[lane + 128]] : -1e30f;
    float m = fmaxf(fmaxf(v0, v1), v2);
#pragma unroll
    for (int off = 32; off; off >>= 1) m = fmaxf(m, __shfl_xor(m, off));
    float e0 = __expf(v0 - m), e1 = __expf(v1 - m);
    float e2 = (lane < 32) ? __expf(v2 - m) : 0.0f;
    float s = e0 + e1 + e2;
#pragma unroll
    for (int off = 32; off; off >>= 1) s += __shfl_xor(s, off);
    float inv = 1.0f / s;
    __hip_bfloat16* o = wsout + ((size_t)f * NB + b) * NEST;
    o[lane]      = __float2bfloat16(e0 * inv);
    o[lane + 64] = __float2bfloat16(e1 * inv);
    if (lane < 32) o[lane + 128] = __float2bfloat16(e2 * inv);
  }
}

// ---------------------------------------------------------------------------
// K0: fragment-pack B operands (runs AFTER k2; overlays w-logits buffer).
//  blocks 0..99 : Bf[f][n=8][kc=5][lane=64][8]  = E[swr[f][kc*32+q*8+j]][n*16+c]
//  block  100   : W1f[n=8][kc=4][lane][8]       = fc1w[kc*32+q*8+j][n*16+c]
//  block  101   : W2f[kc=4][lane][8]            = c<10 ? fc2w[k][c] : 0
//  (lane = q*16+c) -> k3's B loads are base + lane*16, fully coalesced.
// ---------------------------------------------------------------------------
__global__ __launch_bounds__(256) void k0_prep(
    const float* __restrict__ E, const int* __restrict__ swr,
    const float* __restrict__ fc1w, const float* __restrict__ fc2w,
    unsigned short* __restrict__ Bf, unsigned short* __restrict__ W1f,
    unsigned short* __restrict__ W2f)
{
  __shared__ int ridx[NEST];
  const int tid = threadIdx.x;
  const int blk = blockIdx.x;

  if (blk < NFOR) {
    if (tid < NEST) ridx[tid] = swr[blk * NEST + tid];
    __syncthreads();
    for (int m = tid; m < 2560; m += 256) {        // m = (n*5+kc)*64 + lane
      int lane = m & 63, rest = m >> 6;
      int kc = rest % 5, n = rest / 5;
      int q = lane >> 4, c = lane & 15;
      int e0 = kc * 32 + q * 8;
      int h = n * 16 + c;
      union { unsigned short v[8]; uint4 u; } t;
#pragma unroll
      for (int j = 0; j < 8; j++)
        t.v[j] = f2bf(E[(size_t)ridx[e0 + j] * NHID + h]);
      *(uint4*)(Bf + (size_t)blk * 20480 + (size_t)m * 8) = t.u;
    }
  } else if (blk == NFOR) {
    for (int m = tid; m < 2048; m += 256) {        // m = (n*4+kc)*64 + lane
      int lane = m & 63, rest = m >> 6;
      int kc = rest & 3, n = rest >> 2;
      int q = lane >> 4, c = lane & 15;
      int k0 = kc * 32 + q * 8;
      int o = n * 16 + c;
      union { unsigned short v[8]; uint4 u; } t;
#pragma unroll
      for (int j = 0; j < 8; j++)
        t.v[j] = f2bf(fc1w[(size_t)(k0 + j) * NHID + o]);
      *(uint4*)(W1f + (size_t)m * 8) = t.u;
    }
  } else {
    for (int m = tid; m < 256; m += 256) {         // m = kc*64 + lane
      int lane = m & 63, kc = m >> 6;
      int q = lane >> 4, c = lane & 15;
      int k0 = kc * 32 + q * 8;
      union { unsigned short v[8]; uint4 u; } t;
#pragma unroll
      for (int j = 0; j < 8; j++)
        t.v[j] = f2bf(c < NCLS ? fc2w[(size_t)(k0 + j) * NCLS + c] : 0.f);
      *(uint4*)(W2f + (size_t)m * 8) = t.u;
    }
  }
}

// ---------------------------------------------------------------------------
// K3: MFMA-fused, staging-free.  A-frags: GEMM1 direct from row-major ws;
// B-frags: direct from fragment-packed global (L1/L2-hot).  lsA (21.5 KB)
// only holds the wave-private C-layout -> A-layout round-trips.
// ---------------------------------------------------------------------------
__global__ __launch_bounds__(256, 4) void k3_mfma(
    const unsigned short* __restrict__ wsb,   // [f][B][160] bf16
    const unsigned short* __restrict__ Bf,    // [f][8][5][64][8]
    const unsigned short* __restrict__ W1f,   // [8][4][64][8]
    const unsigned short* __restrict__ W2f,   // [4][64][8]
    const float* __restrict__ ln1w, const float* __restrict__ ln1b,
    const float* __restrict__ fc1b,
    const float* __restrict__ ln2w, const float* __restrict__ ln2b,
    const float* __restrict__ fc2b,
    float* __restrict__ out)
{
  __shared__ unsigned short lsA[64 * 168];    // 21504 B

  const int tid = threadIdx.x;
  const int b0 = blockIdx.x * 64;
  const int f  = blockIdx.y;
  const int lane = tid & 63, wv = tid >> 6;
  const int c = lane & 15, q = lane >> 4;

  // ---- GEMM1: F = ws[64x160] @ Ep[160x128], no LDS ----
  const unsigned short* arow =
      wsb + ((size_t)f * NB + b0 + wv * 16 + c) * NEST + q * 8;
  short8 a[5];
#pragma unroll
  for (int kc = 0; kc < 5; kc++) a[kc] = *(const short8*)(arow + kc * 32);

  floatx4 acc[8];
#pragma unroll
  for (int n = 0; n < 8; n++) acc[n] = (floatx4){0.f, 0.f, 0.f, 0.f};

  const unsigned short* bbase = Bf + (size_t)f * 20480 + lane * 8;
#pragma unroll
  for (int n = 0; n < 8; n++) {
    const unsigned short* bp = bbase + n * 2560;
#pragma unroll
    for (int kc = 0; kc < 5; kc++) {
      short8 b = *(const short8*)(bp + kc * 512);
      acc[n] = __builtin_amdgcn_mfma_f32_16x16x32_bf16(a[kc], b, acc[n], 0, 0, 0);
    }
  }

  // ---- LN1 (C-layout: row=q*4+r, col=16n+c; reduce over 16 lanes) ----
  {
    float lw[8], lb[8];
#pragma unroll
    for (int n = 0; n < 8; n++) { lw[n] = ln1w[n * 16 + c]; lb[n] = ln1b[n * 16 + c]; }
#pragma unroll
    for (int r = 0; r < 4; r++) {
      float s1 = 0.f, s2 = 0.f;
#pragma unroll
      for (int n = 0; n < 8; n++) { float v = acc[n][r]; s1 += v; s2 += v * v; }
#pragma unroll
      for (int off = 1; off < 16; off <<= 1) {
        s1 += __shfl_xor(s1, off); s2 += __shfl_xor(s2, off);
      }
      float mu = s1 * (1.f / 128.f);
      float var = fmaxf(s2 * (1.f / 128.f) - mu * mu, 0.f);
      float rs = rsqrtf(var + GEPS);
#pragma unroll
      for (int n = 0; n < 8; n++)
        acc[n][r] = (acc[n][r] - mu) * rs * lw[n] + lb[n];
    }
  }

  // ---- Fn -> lsA (A-layout bf16, wave-private strip) ----
#pragma unroll
  for (int r = 0; r < 4; r++)
#pragma unroll
    for (int n = 0; n < 8; n++)
      lsA[(wv * 16 + q * 4 + r) * 168 + n * 16 + c] = f2bf(acc[n][r]);
  __syncthreads();

  // ---- GEMM2: H = Fn[64x128] @ fc1w[128x128] ----
  const unsigned short* pa = lsA + (wv * 16 + c) * 168 + q * 8;
  short8 a2[4];
#pragma unroll
  for (int kc = 0; kc < 4; kc++) a2[kc] = *(const short8*)(pa + kc * 32);
#pragma unroll
  for (int n = 0; n < 8; n++) acc[n] = (floatx4){0.f, 0.f, 0.f, 0.f};
  const unsigned short* w1p = W1f + lane * 8;
#pragma unroll
  for (int n = 0; n < 8; n++) {
#pragma unroll
    for (int kc = 0; kc < 4; kc++) {
      short8 b = *(const short8*)(w1p + (n * 4 + kc) * 512);
      acc[n] = __builtin_amdgcn_mfma_f32_16x16x32_bf16(a2[kc], b, acc[n], 0, 0, 0);
    }
  }

  // ---- bias + ReLU + LN2 ----
  {
    float fb[8], lw[8], lb[8];
#pragma unroll
    for (int n = 0; n < 8; n++) {
      fb[n] = fc1b[n * 16 + c];
      lw[n] = ln2w[n * 16 + c]; lb[n] = ln2b[n * 16 + c];
    }
#pragma unroll
    for (int r = 0; r < 4; r++) {
#pragma unroll
      for (int n = 0; n < 8; n++) acc[n][r] = fmaxf(acc[n][r] + fb[n], 0.f);
      float s1 = 0.f, s2 = 0.f;
#pragma unroll
      for (int n = 0; n < 8; n++) { float v = acc[n][r]; s1 += v; s2 += v * v; }
#pragma unroll
      for (int off = 1; off < 16; off <<= 1) {
        s1 += __shfl_xor(s1, off); s2 += __shfl_xor(s2, off);
      }
      float mu = s1 * (1.f / 128.f);
      float var = fmaxf(s2 * (1.f / 128.f) - mu * mu, 0.f);
      float rs = rsqrtf(var + GEPS);
#pragma unroll
      for (int n = 0; n < 8; n++)
        acc[n][r] = (acc[n][r] - mu) * rs * lw[n] + lb[n];
    }
  }
  __syncthreads();   // all GEMM2 frag reads done before overwrite

  // ---- H2 -> lsA (A-layout) ----
#pragma unroll
  for (int r = 0; r < 4; r++)
#pragma unroll
    for (int n = 0; n < 8; n++)
      lsA[(wv * 16 + q * 4 + r) * 168 + n * 16 + c] = f2bf(acc[n][r]);
  __syncthreads();

  // ---- fc2 (16-col padded tile) + mean-atomic ----
  short8 a3[4];
#pragma unroll
  for (int kc = 0; kc < 4; kc++) a3[kc] = *(const short8*)(pa + kc * 32);
  floatx4 o4 = (floatx4){0.f, 0.f, 0.f, 0.f};
#pragma unroll
  for (int kc = 0; kc < 4; kc++) {
    short8 b = *(const short8*)(W2f + kc * 512 + lane * 8);
    o4 = __builtin_amdgcn_mfma_f32_16x16x32_bf16(a3[kc], b, o4, 0, 0, 0);
  }
  if (c < NCLS) {
    float bias = fc2b[c];
#pragma unroll
    for (int r = 0; r < 4; r++)
      atomicAdd(out + (size_t)(b0 + wv * 16 + q * 4 + r) * NCLS + c,
                (o4[r] + bias) * 0.01f);
  }
}

// ---------------------------------------------------------------------------
extern "C" void kernel_launch(void* const* d_in, const int* in_sizes, int n_in,
                              void* d_out, int out_size, void* d_ws, size_t ws_size,
                              hipStream_t stream)
{
  (void)in_sizes; (void)n_in; (void)ws_size;
  const float* x    = (const float*)d_in[0];
  const float* w1   = (const float*)d_in[1];
  const float* b1   = (const float*)d_in[2];
  const int*   perm = (const int*)d_in[3];
  const float* gn1w = (const float*)d_in[4];
  const float* gn1b = (const float*)d_in[5];
  const float* c2w  = (const float*)d_in[6];
  const float* c2b  = (const float*)d_in[7];
  const float* gn2w = (const float*)d_in[8];
  const float* gn2b = (const float*)d_in[9];
  const float* c3w  = (const float*)d_in[10];
  const float* c3b  = (const float*)d_in[11];
  const int*   swr  = (const int*)d_in[12];
  const float* E    = (const float*)d_in[13];
  const float* ln1w = (const float*)d_in[14];
  const float* ln1b = (const float*)d_in[15];
  const float* fc1w = (const float*)d_in[16];
  const float* fc1b = (const float*)d_in[17];
  const float* ln2w = (const float*)d_in[18];
  const float* ln2b = (const float*)d_in[19];
  const float* fc2w = (const float*)d_in[20];
  const float* fc2b = (const float*)d_in[21];
  float* out = (float*)d_out;

  // workspace layout:
  //   [0, 26.2MB)  : w logits f32 (k1 -> k2), then overlaid by k0 outputs:
  //                  Bf 4,096,000 B | W1f 32,768 B | W2f 4,096 B
  //   [26.2MB, +131MB) : ws bf16 [f][B][160]
  float* wbuf = (float*)d_ws;
  unsigned short* wsbuf = (unsigned short*)((char*)d_ws + (size_t)NB * NRODT * 4);
  unsigned short* Bfb   = (unsigned short*)d_ws;
  unsigned short* W1fb  = (unsigned short*)((char*)d_ws + 4096000);
  unsigned short* W2fb  = (unsigned short*)((char*)d_ws + 4096000 + 32768);  // W1f is 32768 BYTES (8*4*64*8 shorts)

  hipMemsetAsync(d_out, 0, (size_t)out_size * sizeof(float), stream);
  dim3 g1(NB / 8, 4);
  k1_w<<<g1, 256, 0, stream>>>(x, w1, b1, perm, gn1w, gn1b, c2w, c2b,
                               gn2w, gn2b, c3w, c3b, wbuf);
  k2_softmax<<<NB, 256, 0, stream>>>(wbuf, swr, (__hip_bfloat16*)wsbuf);
  // k0 AFTER k2: it overwrites the w-logits region
  k0_prep<<<NFOR + 2, 256, 0, stream>>>(E, swr, fc1w, fc2w, Bfb, W1fb, W2fb);
  dim3 g3(NB / 64, NFOR);
  k3_mfma<<<g3, 256, 0, stream>>>(wsbuf, Bfb, W1fb, W2fb,
                                  ln1w, ln1b, fc1b, ln2w, ln2b, fc2b, out);
}